// Round 15
// baseline (1035.631 us; speedup 1.0000x reference)
//
#include <hip/hip_runtime.h>

#define H 256
#define FIN 58
#define LN_EPS 1e-5f
#define EPB 8192     // k_b1 edges per block
#define SBW 11       // super-bin width: 2048 dests

typedef __bf16 bf16x8 __attribute__((ext_vector_type(8)));
typedef float f32x16 __attribute__((ext_vector_type(16)));
typedef float f32x2 __attribute__((ext_vector_type(2)));

union FragU {
  ushort u[8];
  bf16x8 v;
};

// ---------------- utilities ----------------

__device__ __forceinline__ float wave_sum(float v) {
#pragma unroll
  for (int off = 1; off < 64; off <<= 1) v += __shfl_xor(v, off, 64);
  return v;
}

__device__ __forceinline__ float half_sum(float v) {
#pragma unroll
  for (int off = 1; off < 32; off <<= 1) v += __shfl_xor(v, off, 64);
  return v;
}

__device__ __forceinline__ float block_sum(float v, volatile float* red) {
  const int tid = threadIdx.x;
  v = wave_sum(v);
  __syncthreads();
  if ((tid & 63) == 0) red[tid >> 6] = v;
  __syncthreads();
  return red[0] + red[1] + red[2] + red[3];
}

__device__ __forceinline__ ushort f2bf(float f) {
  unsigned u = __float_as_uint(f);
  unsigned r = (u + 0x7FFFu + ((u >> 16) & 1u)) >> 16;
  return (ushort)r;
}

__device__ __forceinline__ float bf2f(ushort u) {
  return __uint_as_float((unsigned)u << 16);
}

// ---- fp8 e4m3 pack/unpack (HW path on gfx950, manual fallback) ----
#if __has_builtin(__builtin_amdgcn_cvt_pk_fp8_f32) && __has_builtin(__builtin_amdgcn_cvt_pk_f32_fp8)
__device__ __forceinline__ unsigned pack_fp8x4(float a, float b, float c, float d) {
  int v = 0;
  v = __builtin_amdgcn_cvt_pk_fp8_f32(a, b, v, false);
  v = __builtin_amdgcn_cvt_pk_fp8_f32(c, d, v, true);
  return (unsigned)v;
}
__device__ __forceinline__ void unpack_fp8x2_acc(f32x2& lo, f32x2& hi, unsigned v) {
  lo += __builtin_amdgcn_cvt_pk_f32_fp8((int)v, false);
  hi += __builtin_amdgcn_cvt_pk_f32_fp8((int)v, true);
}
#else
__device__ __forceinline__ unsigned char f2e4m3_1(float f) {
  unsigned u = __float_as_uint(f);
  unsigned s = (u >> 31) << 7;
  float a = fabsf(f);
  if (a >= 448.0f) return (unsigned char)(s | 0x7E);
  if (a < 0.0009765625f) return (unsigned char)s;
  int e;
  float m = frexpf(a, &e);
  int E = e - 1 + 7;
  if (E >= 1) {
    int mm = (int)rintf((m * 2.0f - 1.0f) * 8.0f);
    if (mm == 8) { mm = 0; E++; }
    return (unsigned char)(s | (E << 3) | mm);
  }
  int mm = (int)rintf(a * 512.0f);
  if (mm > 7) return (unsigned char)(s | (1 << 3));
  return (unsigned char)(s | mm);
}
__device__ __forceinline__ unsigned pack_fp8x4(float a, float b, float c, float d) {
  return (unsigned)f2e4m3_1(a) | ((unsigned)f2e4m3_1(b) << 8) |
         ((unsigned)f2e4m3_1(c) << 16) | ((unsigned)f2e4m3_1(d) << 24);
}
__device__ __forceinline__ float e4m3f_1(unsigned v) {
  int s = (v >> 7) & 1, E = (v >> 3) & 15, m = v & 7;
  float mag = E ? ldexpf(1.0f + m * 0.125f, E - 7) : ldexpf((float)m, -9);
  return s ? -mag : mag;
}
__device__ __forceinline__ void unpack_fp8x2_acc(f32x2& lo, f32x2& hi, unsigned v) {
  lo[0] += e4m3f_1(v & 255);
  lo[1] += e4m3f_1((v >> 8) & 255);
  hi[0] += e4m3f_1((v >> 16) & 255);
  hi[1] += e4m3f_1(v >> 24);
}
#endif

// ---------------- setup: radix-style CSR build ----------------

__global__ __launch_bounds__(512) void k_b1(const int* __restrict__ row,
                                            const int* __restrict__ col,
                                            unsigned* __restrict__ breg,
                                            int* __restrict__ gcnt,
                                            int cap2, int E, int nsb) {
  __shared__ unsigned stage[EPB];  // 32 KB
  __shared__ int lh[65], lbase[65], lcur[64], gclaim[64];
  const int tid = threadIdx.x;
  const int e0 = blockIdx.x * EPB;
  const int cnt = min(EPB, E - e0);
  if (tid < 64) lh[tid] = 0;
  __syncthreads();
  for (int i = tid; i < cnt; i += 512) atomicAdd(&lh[col[e0 + i] >> SBW], 1);
  __syncthreads();
  if (tid == 0) {
    int acc = 0;
    for (int b = 0; b < nsb; b++) { lbase[b] = acc; acc += lh[b]; }
    lbase[nsb] = acc;
  }
  __syncthreads();
  if (tid < nsb) {
    gclaim[tid] = atomicAdd(&gcnt[tid], lh[tid]);
    lcur[tid] = lbase[tid];
  }
  __syncthreads();
  for (int i = tid; i < cnt; i += 512) {
    int c = col[e0 + i];
    int b = c >> SBW;
    int s = atomicAdd(&lcur[b], 1);
    stage[s] = ((unsigned)row[e0 + i] << SBW) | (unsigned)(c & ((1 << SBW) - 1));
  }
  __syncthreads();
  for (int i = tid; i < cnt; i += 512) {
    int lo = 0, hi = nsb;
    while (hi - lo > 1) {
      int mid = (lo + hi) >> 1;
      if (lbase[mid] <= i) lo = mid; else hi = mid;
    }
    int off = gclaim[lo] + (i - lbase[lo]);
    if (off < cap2) breg[(size_t)lo * cap2 + off] = stage[i];
  }
}

// per-super-bin degree count + invs (fused)
__global__ __launch_bounds__(512) void k_degB2(const unsigned* __restrict__ breg,
                                               const int* __restrict__ gcnt, int cap2,
                                               int* __restrict__ deg,
                                               float* __restrict__ invs, int N) {
  __shared__ int lcnt[1 << SBW];
  const int b = blockIdx.x, tid = threadIdx.x, base = b << SBW;
  for (int i = tid; i < (1 << SBW); i += 512) lcnt[i] = 0;
  __syncthreads();
  const int cnt = min(gcnt[b], cap2);
  const unsigned* p = breg + (size_t)b * cap2;
  for (int i = tid; i < cnt; i += 512) atomicAdd(&lcnt[p[i] & ((1 << SBW) - 1)], 1);
  __syncthreads();
  for (int i = tid; i < (1 << SBW); i += 512) {
    int d = base + i;
    if (d < N) {
      int c = lcnt[i];
      deg[d] = c;
      invs[d] = (c > 0) ? (1.0f / sqrtf((float)c)) : 0.0f;
    }
  }
}

// level 2: place into final CSR; applies bsum fix-up and writes final offs16 back
__global__ __launch_bounds__(512) void k_b2(const unsigned* __restrict__ breg,
                                            const int* __restrict__ gcnt, int cap2,
                                            int* __restrict__ offs16,
                                            const int* __restrict__ bsum,
                                            int* __restrict__ eb, int N) {
  __shared__ int loffs[1 << SBW];
  __shared__ int lcur[1 << SBW];
  const int b = blockIdx.x, tid = threadIdx.x, base = b << SBW;
  for (int i = tid; i < (1 << SBW); i += 512) {
    int d = base + i;
    if (d < N) {
      int o = offs16[d] + bsum[d >> 10];
      loffs[i] = o;
      offs16[d] = o;  // final value for k_C
    } else {
      loffs[i] = 0;
    }
    lcur[i] = 0;
  }
  __syncthreads();
  const int cnt = min(gcnt[b], cap2);
  const unsigned* p = breg + (size_t)b * cap2;
  for (int i = tid; i < cnt; i += 512) {
    unsigned rc = p[i];
    int lc = rc & ((1 << SBW) - 1);
    int slot = atomicAdd(&lcur[lc], 1);
    eb[loffs[lc] + slot] = (int)(rc >> SBW);
  }
  __syncthreads();
  for (int i = tid; i < (1 << SBW); i += 512) {
    int d = base + i;
    if (d < N) {
      int c = lcur[i];
      int pad = (c + 15) & ~15;
      int o = loffs[i];
      for (int j = c; j < pad; j++) eb[o + j] = N;
    }
  }
}

__global__ __launch_bounds__(1024) void k_scan1(const int* __restrict__ deg,
                                                int* __restrict__ offs16,
                                                int* __restrict__ bsum, int N) {
  __shared__ int buf[1024];
  const int tid = threadIdx.x;
  const int gid = blockIdx.x * 1024 + tid;
  int v = (gid < N) ? ((deg[gid] + 15) & ~15) : 0;
  buf[tid] = v;
  __syncthreads();
  for (int off = 1; off < 1024; off <<= 1) {
    int x = (tid >= off) ? buf[tid - off] : 0;
    __syncthreads();
    buf[tid] += x;
    __syncthreads();
  }
  if (gid < N) offs16[gid] = buf[tid] - v;
  if (tid == 1023) bsum[blockIdx.x] = buf[1023];
}

__global__ __launch_bounds__(1024) void k_scan2(int* __restrict__ bsum, int nb) {
  __shared__ int buf[1024];
  const int tid = threadIdx.x;
  int v = (tid < nb) ? bsum[tid] : 0;
  buf[tid] = v;
  __syncthreads();
  for (int off = 1; off < 1024; off <<= 1) {
    int x = (tid >= off) ? buf[tid - off] : 0;
    __syncthreads();
    buf[tid] += x;
    __syncthreads();
  }
  if (tid < nb) bsum[tid] = buf[tid] - v;
}

// iteration-independent weight products
__global__ void k_prep(const float* __restrict__ Wq, const float* __restrict__ Wk,
                       const float* __restrict__ bq, const float* __restrict__ bk,
                       float* __restrict__ P, float* __restrict__ Q, float* __restrict__ K2,
                       float* __restrict__ pb, float* __restrict__ qb,
                       float* __restrict__ wb, float* __restrict__ kb,
                       float* __restrict__ sconst) {
  __shared__ float red[4];
  const int b = blockIdx.x, tid = threadIdx.x;
  if (b < 768) {
    const int f = b & 255, which = b >> 8;
    const float* A = (which == 2) ? Wk : Wq;
    const float* Bm = (which == 1) ? Wq : Wk;
    float acc = 0.0f;
    for (int m = 0; m < H; m++) acc = fmaf(A[f * H + m], Bm[tid * H + m], acc);
    float* D = (which == 0) ? P : ((which == 1) ? Q : K2);
    D[f * H + tid] = acc;
  } else {
    float a1 = 0, a2 = 0, a3 = 0, a4 = 0;
    for (int m = 0; m < H; m++) {
      float wqv = Wq[tid * H + m], wkv = Wk[tid * H + m];
      a1 = fmaf(wqv, bk[m], a1);
      a2 = fmaf(wqv, bq[m], a2);
      a3 = fmaf(wkv, bq[m], a3);
      a4 = fmaf(wkv, bk[m], a4);
    }
    pb[tid] = a1; qb[tid] = a2; wb[tid] = a3; kb[tid] = a4;
    float c0 = block_sum(bq[tid] * bk[tid], red);
    float c1 = block_sum(bq[tid] * bq[tid], red);
    float c2 = block_sum(bk[tid] * bk[tid], red);
    if (tid == 0) { sconst[0] = c0; sconst[1] = c1; sconst[2] = c2; }
  }
}

// R0 = relu(x@W1 + b1) -> bf16, plus layer-0 readout
__global__ void k_fc1(const float* __restrict__ x, const float* __restrict__ W1,
                      const float* __restrict__ b1, const float* __restrict__ Wr,
                      const float* __restrict__ br, const float* __restrict__ wgt,
                      ushort* __restrict__ R0, float* __restrict__ out, int N) {
  __shared__ __align__(16) float lx[16 * FIN];
  __shared__ float red2[4][16];
  const int tid = threadIdx.x;
  const int n0 = blockIdx.x * 16;
  for (int idx = tid; idx < 16 * FIN / 4; idx += 256)
    ((float4*)lx)[idx] = ((const float4*)(x + (size_t)n0 * FIN))[idx];
  __syncthreads();
  float acc[16];
  const float bias = b1[tid];
#pragma unroll
  for (int r = 0; r < 16; r++) acc[r] = bias;
  for (int f = 0; f < FIN; f++) {
    float wv = W1[f * H + tid];
#pragma unroll
    for (int r = 0; r < 16; r++) acc[r] = fmaf(lx[r * FIN + f], wv, acc[r]);
  }
  const float wr0 = Wr[tid];
#pragma unroll
  for (int r = 0; r < 16; r++) {
    acc[r] = fmaxf(acc[r], 0.0f);
    int n = n0 + r;
    if (n < N) R0[(size_t)n * H + tid] = f2bf(acc[r]);
  }
#pragma unroll
  for (int r = 0; r < 16; r++) {
    float s = wave_sum(acc[r] * wr0);
    if ((tid & 63) == 0) red2[tid >> 6][r] = s;
  }
  __syncthreads();
  if (tid < 16) {
    int n = n0 + tid;
    if (n < N)
      out[n] = wgt[0] * (red2[0][tid] + red2[1][tid] + red2[2][tid] + red2[3][tid] + br[0]);
  }
}

// ---------------- MFMA G = R^T R (transposed-LDS, b128 frags) ----------------
// Even 256-block chunk partition (critical path = ceil(TC/256) chunks).
__global__ __launch_bounds__(512, 2) void k_Gm(const ushort* __restrict__ Rb,
                                               const float* __restrict__ invs,
                                               ushort* __restrict__ Gslab,
                                               unsigned* __restrict__ Rf8,
                                               float* __restrict__ csl, int N) {
  __shared__ ushort sbT[2][256 * 32];  // 2 x 16 KB
  const int tid = threadIdx.x;
  const int lane = tid & 63;
  const int wid = tid >> 6;
  const int wrow = (wid & 1) * 128;
  const int wcol = (wid >> 1) * 64;
  const int l31 = lane & 31;
  const int lhi = lane >> 5;

  const int TC = (N + 31) >> 5;
  const int cbase = TC >> 8;
  const int crem = TC & 255;
  const int b = blockIdx.x;
  const int startc = b * cbase + min(b, crem);
  const int nch = cbase + (b < crem ? 1 : 0);
  const int rowbase = startc * 32;

  const int rp = tid >> 5;   // node pair (nodes 2rp, 2rp+1)
  const int fg = tid & 31;   // feature group (feats fg*8..fg*8+7)
  const int k2 = rp * 2;

  f32x16 acc[4][2];
#pragma unroll
  for (int s = 0; s < 4; s++)
#pragma unroll
    for (int t = 0; t < 2; t++)
#pragma unroll
      for (int e = 0; e < 16; e++) acc[s][t][e] = 0.0f;

  float cs[8];
#pragma unroll
  for (int i = 0; i < 8; i++) cs[i] = 0.0f;

  int4 la, lb;
  float sc0, sc1;

  auto load_chunk = [&](int ch) {
    int g0 = rowbase + ch * 32 + k2;
    const int4* s0 = (const int4*)(Rb + (size_t)g0 * H + fg * 8);
    const int4* s1 = (const int4*)(Rb + (size_t)(g0 + 1) * H + fg * 8);
    la = (g0 < N) ? s0[0] : make_int4(0, 0, 0, 0);
    lb = (g0 + 1 < N) ? s1[0] : make_int4(0, 0, 0, 0);
    sc0 = (g0 < N) ? invs[g0] : 0.0f;
    sc1 = (g0 + 1 < N) ? invs[g0 + 1] : 0.0f;
  };

  auto write_chunk = [&](int ch, int buf) {
    int g0 = rowbase + ch * 32 + k2;
    const ushort* pa = (const ushort*)&la;
    const ushort* pbu = (const ushort*)&lb;
    const int blk = (k2 & 24) ^ ((fg & 3) << 3);
    uint* dst = (uint*)sbT[buf];
#pragma unroll
    for (int i = 0; i < 8; i++) {
      float av = bf2f(pa[i]), bv = bf2f(pbu[i]);
      cs[i] += av + bv;
      unsigned val = (unsigned)pa[i] | ((unsigned)pbu[i] << 16);
      int f = fg * 8 + i;
      dst[f * 16 + ((blk + (k2 & 7)) >> 1)] = val;
    }
    if (g0 < N) {
      unsigned w0 = pack_fp8x4(bf2f(pa[0]) * sc0, bf2f(pa[1]) * sc0,
                               bf2f(pa[2]) * sc0, bf2f(pa[3]) * sc0);
      unsigned w1 = pack_fp8x4(bf2f(pa[4]) * sc0, bf2f(pa[5]) * sc0,
                               bf2f(pa[6]) * sc0, bf2f(pa[7]) * sc0);
      *(uint2*)&Rf8[(size_t)g0 * 64 + fg * 2] = make_uint2(w0, w1);
    }
    if (g0 + 1 < N) {
      unsigned w0 = pack_fp8x4(bf2f(pbu[0]) * sc1, bf2f(pbu[1]) * sc1,
                               bf2f(pbu[2]) * sc1, bf2f(pbu[3]) * sc1);
      unsigned w1 = pack_fp8x4(bf2f(pbu[4]) * sc1, bf2f(pbu[5]) * sc1,
                               bf2f(pbu[6]) * sc1, bf2f(pbu[7]) * sc1);
      *(uint2*)&Rf8[(size_t)(g0 + 1) * 64 + fg * 2] = make_uint2(w0, w1);
    }
  };

  auto compute = [&](int buf) {
    const ushort* bp = sbT[buf];
#pragma unroll
    for (int ks = 0; ks < 2; ks++) {
      const int kb = ks * 16 + lhi * 8;
      FragU fr[6];
#pragma unroll
      for (int s = 0; s < 6; s++) {
        const int cb = (s < 4) ? (wrow + 32 * s + l31) : (wcol + 32 * (s - 4) + l31);
        const int off = cb * 32 + (kb ^ (((cb >> 3) & 3) << 3));
        *(int4*)fr[s].u = *(const int4*)(bp + off);
      }
#pragma unroll
      for (int s = 0; s < 4; s++)
#pragma unroll
        for (int t = 0; t < 2; t++)
          acc[s][t] = __builtin_amdgcn_mfma_f32_32x32x16_bf16(fr[s].v, fr[4 + t].v,
                                                              acc[s][t], 0, 0, 0);
    }
  };

  load_chunk(0);
  write_chunk(0, 0);
  __syncthreads();
  int cur = 0;
  for (int c = 0; c < nch; c++) {
    if (c + 1 < nch) load_chunk(c + 1);
    compute(cur);
    if (c + 1 < nch) write_chunk(c + 1, cur ^ 1);
    __syncthreads();
    cur ^= 1;
  }

  // non-atomic bf16 partial-G slab write
  ushort* Gs = Gslab + (size_t)b * 65536;
#pragma unroll
  for (int s = 0; s < 4; s++)
#pragma unroll
    for (int t = 0; t < 2; t++) {
      const int n0c = wcol + 32 * t + l31;
#pragma unroll
      for (int r = 0; r < 16; r++) {
        const int row = wrow + 32 * s + (r & 3) + 8 * (r >> 2) + 4 * lhi;
        Gs[row * 256 + n0c] = f2bf(acc[s][t][r]);
      }
    }

  // column-sum slab (non-atomic)
  __syncthreads();
  float* fl = (float*)sbT;  // scratch
#pragma unroll
  for (int i = 0; i < 8; i++) fl[rp * 256 + fg * 8 + i] = cs[i];
  __syncthreads();
  if (tid < 256) {
    float v = 0.0f;
    for (int j = 0; j < 16; j++) v += fl[j * 256 + tid];
    csl[(size_t)b * 256 + tid] = v;
  }
}

// reduce bf16 slabs -> fp32 G; also vsum and <G,Q>/<G,K2> partials (non-atomic)
__global__ void k_Gr(const ushort* __restrict__ Gslab, const float* __restrict__ csl,
                     const float* __restrict__ Q, const float* __restrict__ K2,
                     float* __restrict__ G, float* __restrict__ vsum,
                     float2* __restrict__ spart, int nslab) {
  __shared__ float red[4];
  const int b = blockIdx.x, t = threadIdx.x;
  const int i = b * 256 + t;
  float s0 = 0, s1 = 0, s2 = 0, s3 = 0;
  int j = 0;
  for (; j + 3 < nslab; j += 4) {
    s0 += bf2f(Gslab[(size_t)j * 65536 + i]);
    s1 += bf2f(Gslab[(size_t)(j + 1) * 65536 + i]);
    s2 += bf2f(Gslab[(size_t)(j + 2) * 65536 + i]);
    s3 += bf2f(Gslab[(size_t)(j + 3) * 65536 + i]);
  }
  float s = s0 + s1 + s2 + s3;
  for (; j < nslab; j++) s += bf2f(Gslab[(size_t)j * 65536 + i]);
  G[i] = s;
  float dq = block_sum(s * Q[i], red);
  float dk = block_sum(s * K2[i], red);
  if (t == 0) spart[b] = make_float2(dq, dk);
  float v = 0.0f;
  for (int u = t; u < nslab; u += 256) v += csl[(size_t)u * 256 + b];
  v = block_sum(v, red);
  if (t == 0) vsum[b] = v;
}

// per-iteration small products; block 258 finalizes scal
__global__ void k_small(const float* __restrict__ G, const float* __restrict__ vsum,
                        const float* __restrict__ P, const float* __restrict__ pb,
                        const float* __restrict__ wb, const float* __restrict__ sconst,
                        const float* __restrict__ qb, const float* __restrict__ kbv,
                        const float2* __restrict__ spart,
                        ushort* __restrict__ Mt, float* __restrict__ cvec,
                        float* __restrict__ dvec, float* __restrict__ scal, int N) {
  __shared__ float red[4];
  const int b = blockIdx.x, tid = threadIdx.x;
  if (b < 256) {
    float acc = 0.0f;
    for (int m = 0; m < H; m++) acc = fmaf(P[b * H + m], G[m * H + tid], acc);
    Mt[(size_t)tid * H + b] = f2bf(acc + pb[b] * vsum[tid]);
  } else if (b == 256) {
    float acc = 0.0f;
    for (int f = 0; f < H; f++) acc = fmaf(wb[f], G[f * H + tid], acc);
    cvec[tid] = acc + sconst[0] * vsum[tid];
  } else if (b == 257) {
    float acc = 0.0f;
    for (int m = 0; m < H; m++) acc = fmaf(P[tid * H + m], vsum[m], acc);
    dvec[tid] = acc + (float)N * pb[tid];
  } else {
    float2 sp = spart[tid];
    float dq = block_sum(sp.x, red);
    float dk = block_sum(sp.y, red);
    float s1 = block_sum(qb[tid] * vsum[tid], red);
    float s2 = block_sum(kbv[tid] * vsum[tid], red);
    float s3 = block_sum(wb[tid] * vsum[tid], red);
    if (tid == 0) {
      float sq = dq + 2.0f * s1 + (float)N * sconst[1];
      float sk = dk + 2.0f * s2 + (float)N * sconst[2];
      scal[2] = 1.0f / (sqrtf(sq) * sqrtf(sk));
      scal[3] = s3 + (float)N * sconst[0];
    }
  }
}

// fused k_C: phase 1 MFMA -> bf16 LDS; pass A (pre-barrier) den + fp8 gather
// into registers (overlaps other waves' MFMA); barrier; pass B combine+LN.
__global__ __launch_bounds__(256, 4) void k_C(
    const ushort* __restrict__ Rb, ushort* __restrict__ Rnext,
    const ushort* __restrict__ Mt, const unsigned* __restrict__ Rf8,
    const int* __restrict__ eb, const float* __restrict__ invs,
    const float* __restrict__ cvec, const float* __restrict__ dvec,
    const float* __restrict__ vsum, const float* __restrict__ scal,
    const int* __restrict__ offs16, const int* __restrict__ deg,
    const float* __restrict__ alphap, const float* __restrict__ gamma,
    const float* __restrict__ beta, const float* __restrict__ Wr,
    const float* __restrict__ br, const float* __restrict__ wgt,
    float* __restrict__ out, int N, int layer, int last) {
  __shared__ __align__(16) ushort lnum[32 * 256];  // 16 KB (bf16)
  const int tid = threadIdx.x, lane = tid & 63, wv = tid >> 6;
  const int half = lane >> 5, hl = lane & 31;
  const int d0 = hl * 8;
  const int nb0 = blockIdx.x * 32;

  // ---- phase 1: num tile via MFMA (A rows from Rb, B cols from Mt[n][k]) ----
  {
    f32x16 a0, a1;
#pragma unroll
    for (int e = 0; e < 16; e++) { a0[e] = 0.0f; a1[e] = 0.0f; }
    const int wcol = wv * 64;
    const ushort* aptr = Rb + (size_t)(nb0 + hl) * H;  // rows beyond N: garbage ok (unread)
    const ushort* bptr0 = Mt + (size_t)(wcol + hl) * H;
    const ushort* bptr1 = Mt + (size_t)(wcol + 32 + hl) * H;
    for (int kc = 0; kc < 16; kc++) {
      const int kb = kc * 16 + half * 8;
      FragU fa, fb0, fb1;
      *(int4*)fa.u = *(const int4*)(aptr + kb);
      *(int4*)fb0.u = *(const int4*)(bptr0 + kb);
      *(int4*)fb1.u = *(const int4*)(bptr1 + kb);
      a0 = __builtin_amdgcn_mfma_f32_32x32x16_bf16(fa.v, fb0.v, a0, 0, 0, 0);
      a1 = __builtin_amdgcn_mfma_f32_32x32x16_bf16(fa.v, fb1.v, a1, 0, 0, 0);
    }
#pragma unroll
    for (int r = 0; r < 16; r++) {
      const int row = (r & 3) + 8 * (r >> 2) + 4 * half;
      lnum[row * 256 + wcol + hl] = f2bf(a0[r]);
      lnum[row * 256 + wcol + 32 + hl] = f2bf(a1[r]);
    }
  }

  const float invn = scal[2], denc = scal[3];
  const float al = alphap[0], om = 1.0f - al;

  // ---- pass A (pre-barrier): den + gather into registers for 4 rows ----
  float den[4];
  float ag[4][8];
  {
    const float4 dvA = *(const float4*)&dvec[d0];
    const float4 dvB = *(const float4*)&dvec[d0 + 4];
#pragma unroll
    for (int r = 0; r < 4; r++) {
      const int lr = wv * 8 + r * 2 + half;
      const int n = nb0 + lr;
      const bool valid = n < N;
      const int ns = valid ? n : 0;

      const int4 rv = *(const int4*)&Rb[(size_t)ns * H + d0];
      const ushort* rp = (const ushort*)&rv;
      float p = bf2f(rp[0]) * dvA.x + bf2f(rp[1]) * dvA.y + bf2f(rp[2]) * dvA.z +
                bf2f(rp[3]) * dvA.w + bf2f(rp[4]) * dvB.x + bf2f(rp[5]) * dvB.y +
                bf2f(rp[6]) * dvB.z + bf2f(rp[7]) * dvB.w;
      p = half_sum(p);
      den[r] = 1.0f / ((p + denc) * invn + (float)N);

      f32x2 a01 = {0.f, 0.f}, a23 = {0.f, 0.f}, a45 = {0.f, 0.f}, a67 = {0.f, 0.f};
      const int st = offs16[ns];
      const int nbch = valid ? ((deg[ns] + 15) >> 4) : 0;
      const int4* pe = (const int4*)(eb + st);
      const int woff = hl * 2;
      for (int b = 0; b < nbch; b++, pe += 4) {
        int4 q0 = pe[0], q1 = pe[1], q2 = pe[2], q3 = pe[3];
        const int srcs[16] = {q0.x, q0.y, q0.z, q0.w, q1.x, q1.y, q1.z, q1.w,
                              q2.x, q2.y, q2.z, q2.w, q3.x, q3.y, q3.z, q3.w};
        uint2 g[16];
#pragma unroll
        for (int i = 0; i < 16; i++)
          g[i] = *(const uint2*)&Rf8[((size_t)srcs[i] << 6) + woff];
#pragma unroll
        for (int i = 0; i < 16; i++) {
          unpack_fp8x2_acc(a01, a23, g[i].x);
          unpack_fp8x2_acc(a45, a67, g[i].y);
        }
      }
      const float sn = invs[ns];
      ag[r][0] = a01[0] * sn; ag[r][1] = a01[1] * sn;
      ag[r][2] = a23[0] * sn; ag[r][3] = a23[1] * sn;
      ag[r][4] = a45[0] * sn; ag[r][5] = a45[1] * sn;
      ag[r][6] = a67[0] * sn; ag[r][7] = a67[1] * sn;
    }
  }
  __syncthreads();

  // ---- pass B: combine with lnum, LN, write, readout ----
  const float4 cvA = *(const float4*)&cvec[d0];
  const float4 cvB = *(const float4*)&cvec[d0 + 4];
  const float4 vsA = *(const float4*)&vsum[d0];
  const float4 vsB = *(const float4*)&vsum[d0 + 4];
  const float4 gmA = *(const float4*)&gamma[d0];
  const float4 gmB = *(const float4*)&gamma[d0 + 4];
  const float4 btA = *(const float4*)&beta[d0];
  const float4 btB = *(const float4*)&beta[d0 + 4];
  const float4 wrA = *(const float4*)&Wr[layer * H + d0];
  const float4 wrB = *(const float4*)&Wr[layer * H + d0 + 4];
  const float wl = wgt[layer], bl = br[layer];
  const float cva[8] = {cvA.x, cvA.y, cvA.z, cvA.w, cvB.x, cvB.y, cvB.z, cvB.w};
  const float vsa[8] = {vsA.x, vsA.y, vsA.z, vsA.w, vsB.x, vsB.y, vsB.z, vsB.w};
  const float gma[8] = {gmA.x, gmA.y, gmA.z, gmA.w, gmB.x, gmB.y, gmB.z, gmB.w};
  const float bta[8] = {btA.x, btA.y, btA.z, btA.w, btB.x, btB.y, btB.z, btB.w};
  const float wra[8] = {wrA.x, wrA.y, wrA.z, wrA.w, wrB.x, wrB.y, wrB.z, wrB.w};

#pragma unroll
  for (int r = 0; r < 4; r++) {
    const int lr = wv * 8 + r * 2 + half;
    const int n = nb0 + lr;
    const bool valid = n < N;
    const int ns = valid ? n : 0;

    const int4 rv = *(const int4*)&Rb[(size_t)ns * H + d0];  // L1-hot reload
    const ushort* rp = (const ushort*)&rv;
    const int4 nv = *(const int4*)&lnum[lr * 256 + d0];
    const ushort* np = (const ushort*)&nv;
    const float rden = den[r];

    float hv[8];
#pragma unroll
    for (int j = 0; j < 8; j++)
      hv[j] = al * (((bf2f(np[j]) + cva[j]) * invn + vsa[j]) * rden + ag[r][j]) +
              om * bf2f(rp[j]);

    float s = 0.0f, s2 = 0.0f;
#pragma unroll
    for (int j = 0; j < 8; j++) { s += hv[j]; s2 += hv[j] * hv[j]; }
    s = half_sum(s);
    s2 = half_sum(s2);
    const float mu = s * (1.0f / H);
    const float var = s2 * (1.0f / H) - mu * mu;
    const float rs = rsqrtf(var + LN_EPS);

    float y[8], rp2 = 0.0f;
    ushort yo[8];
#pragma unroll
    for (int j = 0; j < 8; j++) {
      y[j] = (hv[j] - mu) * rs * gma[j] + bta[j];
      yo[j] = f2bf(y[j]);
      rp2 += y[j] * wra[j];
    }
    if (!last && valid) *(int4*)&Rnext[(size_t)n * H + d0] = *(int4*)yo;
    rp2 = half_sum(rp2);
    if (hl == 0 && valid) out[n] += wl * (rp2 + bl);
  }
}

// ---------------- host ----------------

extern "C" void kernel_launch(void* const* d_in, const int* in_sizes, int n_in,
                              void* d_out, int out_size, void* d_ws, size_t ws_size,
                              hipStream_t stream) {
  const float* x = (const float*)d_in[0];
  const int* ei = (const int*)d_in[1];
  const float* W1 = (const float*)d_in[2];
  const float* b1 = (const float*)d_in[3];
  const float* Wq = (const float*)d_in[4];
  const float* bq = (const float*)d_in[5];
  const float* Wk = (const float*)d_in[6];
  const float* bk = (const float*)d_in[7];
  const float* gamma = (const float*)d_in[8];
  const float* beta = (const float*)d_in[9];
  const float* alphap = (const float*)d_in[10];
  const float* Wr = (const float*)d_in[11];
  const float* br = (const float*)d_in[12];
  const float* wgt = (const float*)d_in[13];
  float* out = (float*)d_out;

  const int N = in_sizes[0] / FIN;
  const int E = in_sizes[1] / 2;
  const int* row = ei;
  const int* col = ei + E;

  char* w = (char*)d_ws;
  auto alloc = [&](size_t bytes) -> char* {
    char* p = w;
    w += (bytes + 255) & ~(size_t)255;
    return p;
  };
  const size_t RB = (size_t)(N + 128) * H * sizeof(ushort);
  ushort* Rb0 = (ushort*)alloc(RB);
  ushort* Rb1 = (ushort*)alloc(RB);   // aliased as super-bin record scratch in setup
  ushort* Gslab = (ushort*)alloc((size_t)256 * 65536 * sizeof(ushort));  // 32 MB
  unsigned* Rf8 = (unsigned*)alloc((size_t)(N + 1) * 64 * sizeof(unsigned));  // +1 zero row
  ushort* Mt = (ushort*)alloc(H * H * sizeof(ushort));
  float* G = (float*)alloc(H * H * sizeof(float));
  float* vsum = (float*)alloc(1024);
  float* scal = (float*)alloc(256);
  float* cvec = (float*)alloc(1024);
  float* dvec = (float*)alloc(1024);
  float* P = (float*)alloc(H * H * sizeof(float));
  float* Q = (float*)alloc(H * H * sizeof(float));
  float* K2 = (float*)alloc(H * H * sizeof(float));
  float* pb = (float*)alloc(1024);
  float* qb = (float*)alloc(1024);
  float* wb = (float*)alloc(1024);
  float* kb = (float*)alloc(1024);
  float* sconst = (float*)alloc(256);
  int* deg = (int*)alloc((size_t)N * 4);
  float* invs = (float*)alloc((size_t)N * 4);
  int* offs16 = (int*)alloc((size_t)(N + 1) * 4);
  int* bsum = (int*)alloc(1024 * 4);
  int* gcnt = (int*)alloc(64 * 4);
  const int nbG = 256;  // even chunk partition
  float* csl = (float*)alloc((size_t)nbG * 256 * sizeof(float));
  float2* spart = (float2*)alloc(256 * sizeof(float2));
  size_t EPAD = (size_t)E + 16 * (size_t)N;
  EPAD = (EPAD + 3) & ~(size_t)3;
  int* eb = (int*)alloc(EPAD * sizeof(int));

  const int NSB = (N + (1 << SBW) - 1) >> SBW;  // super-bins (<=64 for N<=131072)
  int cap2 = (E / (NSB > 0 ? NSB : 1)) * 2 + 4096;
  cap2 = (cap2 + 3) & ~3;
  unsigned* breg = (unsigned*)Rb1;  // NSB*cap2*4B <= RB

  hipMemsetAsync(gcnt, 0, 64 * 4, stream);
  hipMemsetAsync(Rf8 + (size_t)N * 64, 0, 64 * sizeof(unsigned), stream);

  const int nblk = (N + 1023) / 1024;
  const int nbB1 = (E + EPB - 1) / EPB;
  k_b1<<<nbB1, 512, 0, stream>>>(row, col, breg, gcnt, cap2, E, NSB);
  k_degB2<<<NSB, 512, 0, stream>>>(breg, gcnt, cap2, deg, invs, N);
  k_scan1<<<nblk, 1024, 0, stream>>>(deg, offs16, bsum, N);
  k_scan2<<<1, 1024, 0, stream>>>(bsum, nblk);
  k_b2<<<NSB, 512, 0, stream>>>(breg, gcnt, cap2, offs16, bsum, eb, N);
  k_prep<<<769, 256, 0, stream>>>(Wq, Wk, bq, bk, P, Q, K2, pb, qb, wb, kb, sconst);
  const int gRows16 = (N + 15) / 16;
  k_fc1<<<gRows16, 256, 0, stream>>>(x, W1, b1, Wr, br, wgt, Rb0, out, N);

  const int gRows32 = (N + 31) / 32;
  ushort* Rc = Rb0;
  ushort* Rn = Rb1;
  for (int it = 1; it <= 3; ++it) {
    k_Gm<<<nbG, 512, 0, stream>>>(Rc, invs, Gslab, Rf8, csl, N);
    k_Gr<<<256, 256, 0, stream>>>(Gslab, csl, Q, K2, G, vsum, spart, nbG);
    k_small<<<259, 256, 0, stream>>>(G, vsum, P, pb, wb, sconst, qb, kb, spart,
                                     Mt, cvec, dvec, scal, N);
    k_C<<<gRows32, 256, 0, stream>>>(Rc, Rn, Mt, Rf8, eb, invs, cvec, dvec, vsum, scal,
                                     offs16, deg, alphap, gamma, beta, Wr, br, wgt, out,
                                     N, it, (it == 3) ? 1 : 0);
    ushort* t = Rc; Rc = Rn; Rn = t;
  }
}

// Round 16
// 1030.788 us; speedup vs baseline: 1.0047x; 1.0047x over previous
//
#include <hip/hip_runtime.h>

#define H 256
#define FIN 58
#define LN_EPS 1e-5f
#define EPB 8192     // k_b1 edges per block
#define SBW 11       // super-bin width: 2048 dests

typedef __bf16 bf16x8 __attribute__((ext_vector_type(8)));
typedef float f32x16 __attribute__((ext_vector_type(16)));
typedef float f32x2 __attribute__((ext_vector_type(2)));

union FragU {
  ushort u[8];
  bf16x8 v;
};

// ---------------- utilities ----------------

__device__ __forceinline__ float wave_sum(float v) {
#pragma unroll
  for (int off = 1; off < 64; off <<= 1) v += __shfl_xor(v, off, 64);
  return v;
}

__device__ __forceinline__ float half_sum(float v) {
#pragma unroll
  for (int off = 1; off < 32; off <<= 1) v += __shfl_xor(v, off, 64);
  return v;
}

__device__ __forceinline__ float block_sum(float v, volatile float* red) {
  const int tid = threadIdx.x;
  v = wave_sum(v);
  __syncthreads();
  if ((tid & 63) == 0) red[tid >> 6] = v;
  __syncthreads();
  return red[0] + red[1] + red[2] + red[3];
}

__device__ __forceinline__ ushort f2bf(float f) {
  unsigned u = __float_as_uint(f);
  unsigned r = (u + 0x7FFFu + ((u >> 16) & 1u)) >> 16;
  return (ushort)r;
}

__device__ __forceinline__ float bf2f(ushort u) {
  return __uint_as_float((unsigned)u << 16);
}

// ---- fp8 e4m3 pack/unpack (HW path on gfx950, manual fallback) ----
#if __has_builtin(__builtin_amdgcn_cvt_pk_fp8_f32) && __has_builtin(__builtin_amdgcn_cvt_pk_f32_fp8)
__device__ __forceinline__ unsigned pack_fp8x4(float a, float b, float c, float d) {
  int v = 0;
  v = __builtin_amdgcn_cvt_pk_fp8_f32(a, b, v, false);
  v = __builtin_amdgcn_cvt_pk_fp8_f32(c, d, v, true);
  return (unsigned)v;
}
__device__ __forceinline__ void unpack_fp8x2_acc(f32x2& lo, f32x2& hi, unsigned v) {
  lo += __builtin_amdgcn_cvt_pk_f32_fp8((int)v, false);
  hi += __builtin_amdgcn_cvt_pk_f32_fp8((int)v, true);
}
#else
__device__ __forceinline__ unsigned char f2e4m3_1(float f) {
  unsigned u = __float_as_uint(f);
  unsigned s = (u >> 31) << 7;
  float a = fabsf(f);
  if (a >= 448.0f) return (unsigned char)(s | 0x7E);
  if (a < 0.0009765625f) return (unsigned char)s;
  int e;
  float m = frexpf(a, &e);
  int E = e - 1 + 7;
  if (E >= 1) {
    int mm = (int)rintf((m * 2.0f - 1.0f) * 8.0f);
    if (mm == 8) { mm = 0; E++; }
    return (unsigned char)(s | (E << 3) | mm);
  }
  int mm = (int)rintf(a * 512.0f);
  if (mm > 7) return (unsigned char)(s | (1 << 3));
  return (unsigned char)(s | mm);
}
__device__ __forceinline__ unsigned pack_fp8x4(float a, float b, float c, float d) {
  return (unsigned)f2e4m3_1(a) | ((unsigned)f2e4m3_1(b) << 8) |
         ((unsigned)f2e4m3_1(c) << 16) | ((unsigned)f2e4m3_1(d) << 24);
}
__device__ __forceinline__ float e4m3f_1(unsigned v) {
  int s = (v >> 7) & 1, E = (v >> 3) & 15, m = v & 7;
  float mag = E ? ldexpf(1.0f + m * 0.125f, E - 7) : ldexpf((float)m, -9);
  return s ? -mag : mag;
}
__device__ __forceinline__ void unpack_fp8x2_acc(f32x2& lo, f32x2& hi, unsigned v) {
  lo[0] += e4m3f_1(v & 255);
  lo[1] += e4m3f_1((v >> 8) & 255);
  hi[0] += e4m3f_1((v >> 16) & 255);
  hi[1] += e4m3f_1(v >> 24);
}
#endif

// ---------------- setup: radix-style CSR build ----------------

__global__ __launch_bounds__(512) void k_b1(const int* __restrict__ row,
                                            const int* __restrict__ col,
                                            unsigned* __restrict__ breg,
                                            int* __restrict__ gcnt,
                                            int cap2, int E, int nsb) {
  __shared__ unsigned stage[EPB];  // 32 KB
  __shared__ int lh[65], lbase[65], lcur[64], gclaim[64];
  const int tid = threadIdx.x;
  const int e0 = blockIdx.x * EPB;
  const int cnt = min(EPB, E - e0);
  if (tid < 64) lh[tid] = 0;
  __syncthreads();
  for (int i = tid; i < cnt; i += 512) atomicAdd(&lh[col[e0 + i] >> SBW], 1);
  __syncthreads();
  if (tid == 0) {
    int acc = 0;
    for (int b = 0; b < nsb; b++) { lbase[b] = acc; acc += lh[b]; }
    lbase[nsb] = acc;
  }
  __syncthreads();
  if (tid < nsb) {
    gclaim[tid] = atomicAdd(&gcnt[tid], lh[tid]);
    lcur[tid] = lbase[tid];
  }
  __syncthreads();
  for (int i = tid; i < cnt; i += 512) {
    int c = col[e0 + i];
    int b = c >> SBW;
    int s = atomicAdd(&lcur[b], 1);
    stage[s] = ((unsigned)row[e0 + i] << SBW) | (unsigned)(c & ((1 << SBW) - 1));
  }
  __syncthreads();
  for (int i = tid; i < cnt; i += 512) {
    int lo = 0, hi = nsb;
    while (hi - lo > 1) {
      int mid = (lo + hi) >> 1;
      if (lbase[mid] <= i) lo = mid; else hi = mid;
    }
    int off = gclaim[lo] + (i - lbase[lo]);
    if (off < cap2) breg[(size_t)lo * cap2 + off] = stage[i];
  }
}

// per-super-bin degree count + invs (fused)
__global__ __launch_bounds__(512) void k_degB2(const unsigned* __restrict__ breg,
                                               const int* __restrict__ gcnt, int cap2,
                                               int* __restrict__ deg,
                                               float* __restrict__ invs, int N) {
  __shared__ int lcnt[1 << SBW];
  const int b = blockIdx.x, tid = threadIdx.x, base = b << SBW;
  for (int i = tid; i < (1 << SBW); i += 512) lcnt[i] = 0;
  __syncthreads();
  const int cnt = min(gcnt[b], cap2);
  const unsigned* p = breg + (size_t)b * cap2;
  for (int i = tid; i < cnt; i += 512) atomicAdd(&lcnt[p[i] & ((1 << SBW) - 1)], 1);
  __syncthreads();
  for (int i = tid; i < (1 << SBW); i += 512) {
    int d = base + i;
    if (d < N) {
      int c = lcnt[i];
      deg[d] = c;
      invs[d] = (c > 0) ? (1.0f / sqrtf((float)c)) : 0.0f;
    }
  }
}

// level 2: place into final CSR; applies bsum fix-up and writes final offs16 back
__global__ __launch_bounds__(512) void k_b2(const unsigned* __restrict__ breg,
                                            const int* __restrict__ gcnt, int cap2,
                                            int* __restrict__ offs16,
                                            const int* __restrict__ bsum,
                                            int* __restrict__ eb, int N) {
  __shared__ int loffs[1 << SBW];
  __shared__ int lcur[1 << SBW];
  const int b = blockIdx.x, tid = threadIdx.x, base = b << SBW;
  for (int i = tid; i < (1 << SBW); i += 512) {
    int d = base + i;
    if (d < N) {
      int o = offs16[d] + bsum[d >> 10];
      loffs[i] = o;
      offs16[d] = o;  // final value for k_C
    } else {
      loffs[i] = 0;
    }
    lcur[i] = 0;
  }
  __syncthreads();
  const int cnt = min(gcnt[b], cap2);
  const unsigned* p = breg + (size_t)b * cap2;
  for (int i = tid; i < cnt; i += 512) {
    unsigned rc = p[i];
    int lc = rc & ((1 << SBW) - 1);
    int slot = atomicAdd(&lcur[lc], 1);
    eb[loffs[lc] + slot] = (int)(rc >> SBW);
  }
  __syncthreads();
  for (int i = tid; i < (1 << SBW); i += 512) {
    int d = base + i;
    if (d < N) {
      int c = lcur[i];
      int pad = (c + 15) & ~15;
      int o = loffs[i];
      for (int j = c; j < pad; j++) eb[o + j] = N;
    }
  }
}

__global__ __launch_bounds__(1024) void k_scan1(const int* __restrict__ deg,
                                                int* __restrict__ offs16,
                                                int* __restrict__ bsum, int N) {
  __shared__ int buf[1024];
  const int tid = threadIdx.x;
  const int gid = blockIdx.x * 1024 + tid;
  int v = (gid < N) ? ((deg[gid] + 15) & ~15) : 0;
  buf[tid] = v;
  __syncthreads();
  for (int off = 1; off < 1024; off <<= 1) {
    int x = (tid >= off) ? buf[tid - off] : 0;
    __syncthreads();
    buf[tid] += x;
    __syncthreads();
  }
  if (gid < N) offs16[gid] = buf[tid] - v;
  if (tid == 1023) bsum[blockIdx.x] = buf[1023];
}

__global__ __launch_bounds__(1024) void k_scan2(int* __restrict__ bsum, int nb) {
  __shared__ int buf[1024];
  const int tid = threadIdx.x;
  int v = (tid < nb) ? bsum[tid] : 0;
  buf[tid] = v;
  __syncthreads();
  for (int off = 1; off < 1024; off <<= 1) {
    int x = (tid >= off) ? buf[tid - off] : 0;
    __syncthreads();
    buf[tid] += x;
    __syncthreads();
  }
  if (tid < nb) bsum[tid] = buf[tid] - v;
}

// iteration-independent weight products
__global__ void k_prep(const float* __restrict__ Wq, const float* __restrict__ Wk,
                       const float* __restrict__ bq, const float* __restrict__ bk,
                       float* __restrict__ P, float* __restrict__ Q, float* __restrict__ K2,
                       float* __restrict__ pb, float* __restrict__ qb,
                       float* __restrict__ wb, float* __restrict__ kb,
                       float* __restrict__ sconst) {
  __shared__ float red[4];
  const int b = blockIdx.x, tid = threadIdx.x;
  if (b < 768) {
    const int f = b & 255, which = b >> 8;
    const float* A = (which == 2) ? Wk : Wq;
    const float* Bm = (which == 1) ? Wq : Wk;
    float acc = 0.0f;
    for (int m = 0; m < H; m++) acc = fmaf(A[f * H + m], Bm[tid * H + m], acc);
    float* D = (which == 0) ? P : ((which == 1) ? Q : K2);
    D[f * H + tid] = acc;
  } else {
    float a1 = 0, a2 = 0, a3 = 0, a4 = 0;
    for (int m = 0; m < H; m++) {
      float wqv = Wq[tid * H + m], wkv = Wk[tid * H + m];
      a1 = fmaf(wqv, bk[m], a1);
      a2 = fmaf(wqv, bq[m], a2);
      a3 = fmaf(wkv, bq[m], a3);
      a4 = fmaf(wkv, bk[m], a4);
    }
    pb[tid] = a1; qb[tid] = a2; wb[tid] = a3; kb[tid] = a4;
    float c0 = block_sum(bq[tid] * bk[tid], red);
    float c1 = block_sum(bq[tid] * bq[tid], red);
    float c2 = block_sum(bk[tid] * bk[tid], red);
    if (tid == 0) { sconst[0] = c0; sconst[1] = c1; sconst[2] = c2; }
  }
}

// R0 = relu(x@W1 + b1) -> bf16, plus layer-0 readout
__global__ void k_fc1(const float* __restrict__ x, const float* __restrict__ W1,
                      const float* __restrict__ b1, const float* __restrict__ Wr,
                      const float* __restrict__ br, const float* __restrict__ wgt,
                      ushort* __restrict__ R0, float* __restrict__ out, int N) {
  __shared__ __align__(16) float lx[16 * FIN];
  __shared__ float red2[4][16];
  const int tid = threadIdx.x;
  const int n0 = blockIdx.x * 16;
  for (int idx = tid; idx < 16 * FIN / 4; idx += 256)
    ((float4*)lx)[idx] = ((const float4*)(x + (size_t)n0 * FIN))[idx];
  __syncthreads();
  float acc[16];
  const float bias = b1[tid];
#pragma unroll
  for (int r = 0; r < 16; r++) acc[r] = bias;
  for (int f = 0; f < FIN; f++) {
    float wv = W1[f * H + tid];
#pragma unroll
    for (int r = 0; r < 16; r++) acc[r] = fmaf(lx[r * FIN + f], wv, acc[r]);
  }
  const float wr0 = Wr[tid];
#pragma unroll
  for (int r = 0; r < 16; r++) {
    acc[r] = fmaxf(acc[r], 0.0f);
    int n = n0 + r;
    if (n < N) R0[(size_t)n * H + tid] = f2bf(acc[r]);
  }
#pragma unroll
  for (int r = 0; r < 16; r++) {
    float s = wave_sum(acc[r] * wr0);
    if ((tid & 63) == 0) red2[tid >> 6][r] = s;
  }
  __syncthreads();
  if (tid < 16) {
    int n = n0 + tid;
    if (n < N)
      out[n] = wgt[0] * (red2[0][tid] + red2[1][tid] + red2[2][tid] + red2[3][tid] + br[0]);
  }
}

// ---------------- MFMA G = R^T R (transposed-LDS, b128 frags) ----------------
// Even 256-block chunk partition (critical path = ceil(TC/256) chunks).
__global__ __launch_bounds__(512, 2) void k_Gm(const ushort* __restrict__ Rb,
                                               const float* __restrict__ invs,
                                               ushort* __restrict__ Gslab,
                                               unsigned* __restrict__ Rf8,
                                               float* __restrict__ csl, int N) {
  __shared__ ushort sbT[2][256 * 32];  // 2 x 16 KB
  const int tid = threadIdx.x;
  const int lane = tid & 63;
  const int wid = tid >> 6;
  const int wrow = (wid & 1) * 128;
  const int wcol = (wid >> 1) * 64;
  const int l31 = lane & 31;
  const int lhi = lane >> 5;

  const int TC = (N + 31) >> 5;
  const int cbase = TC >> 8;
  const int crem = TC & 255;
  const int b = blockIdx.x;
  const int startc = b * cbase + min(b, crem);
  const int nch = cbase + (b < crem ? 1 : 0);
  const int rowbase = startc * 32;

  const int rp = tid >> 5;   // node pair (nodes 2rp, 2rp+1)
  const int fg = tid & 31;   // feature group (feats fg*8..fg*8+7)
  const int k2 = rp * 2;

  f32x16 acc[4][2];
#pragma unroll
  for (int s = 0; s < 4; s++)
#pragma unroll
    for (int t = 0; t < 2; t++)
#pragma unroll
      for (int e = 0; e < 16; e++) acc[s][t][e] = 0.0f;

  float cs[8];
#pragma unroll
  for (int i = 0; i < 8; i++) cs[i] = 0.0f;

  int4 la, lb;
  float sc0, sc1;

  auto load_chunk = [&](int ch) {
    int g0 = rowbase + ch * 32 + k2;
    const int4* s0 = (const int4*)(Rb + (size_t)g0 * H + fg * 8);
    const int4* s1 = (const int4*)(Rb + (size_t)(g0 + 1) * H + fg * 8);
    la = (g0 < N) ? s0[0] : make_int4(0, 0, 0, 0);
    lb = (g0 + 1 < N) ? s1[0] : make_int4(0, 0, 0, 0);
    sc0 = (g0 < N) ? invs[g0] : 0.0f;
    sc1 = (g0 + 1 < N) ? invs[g0 + 1] : 0.0f;
  };

  auto write_chunk = [&](int ch, int buf) {
    int g0 = rowbase + ch * 32 + k2;
    const ushort* pa = (const ushort*)&la;
    const ushort* pbu = (const ushort*)&lb;
    const int blk = (k2 & 24) ^ ((fg & 3) << 3);
    uint* dst = (uint*)sbT[buf];
#pragma unroll
    for (int i = 0; i < 8; i++) {
      float av = bf2f(pa[i]), bv = bf2f(pbu[i]);
      cs[i] += av + bv;
      unsigned val = (unsigned)pa[i] | ((unsigned)pbu[i] << 16);
      int f = fg * 8 + i;
      dst[f * 16 + ((blk + (k2 & 7)) >> 1)] = val;
    }
    if (g0 < N) {
      unsigned w0 = pack_fp8x4(bf2f(pa[0]) * sc0, bf2f(pa[1]) * sc0,
                               bf2f(pa[2]) * sc0, bf2f(pa[3]) * sc0);
      unsigned w1 = pack_fp8x4(bf2f(pa[4]) * sc0, bf2f(pa[5]) * sc0,
                               bf2f(pa[6]) * sc0, bf2f(pa[7]) * sc0);
      *(uint2*)&Rf8[(size_t)g0 * 64 + fg * 2] = make_uint2(w0, w1);
    }
    if (g0 + 1 < N) {
      unsigned w0 = pack_fp8x4(bf2f(pbu[0]) * sc1, bf2f(pbu[1]) * sc1,
                               bf2f(pbu[2]) * sc1, bf2f(pbu[3]) * sc1);
      unsigned w1 = pack_fp8x4(bf2f(pbu[4]) * sc1, bf2f(pbu[5]) * sc1,
                               bf2f(pbu[6]) * sc1, bf2f(pbu[7]) * sc1);
      *(uint2*)&Rf8[(size_t)(g0 + 1) * 64 + fg * 2] = make_uint2(w0, w1);
    }
  };

  auto compute = [&](int buf) {
    const ushort* bp = sbT[buf];
#pragma unroll
    for (int ks = 0; ks < 2; ks++) {
      const int kb = ks * 16 + lhi * 8;
      FragU fr[6];
#pragma unroll
      for (int s = 0; s < 6; s++) {
        const int cb = (s < 4) ? (wrow + 32 * s + l31) : (wcol + 32 * (s - 4) + l31);
        const int off = cb * 32 + (kb ^ (((cb >> 3) & 3) << 3));
        *(int4*)fr[s].u = *(const int4*)(bp + off);
      }
#pragma unroll
      for (int s = 0; s < 4; s++)
#pragma unroll
        for (int t = 0; t < 2; t++)
          acc[s][t] = __builtin_amdgcn_mfma_f32_32x32x16_bf16(fr[s].v, fr[4 + t].v,
                                                              acc[s][t], 0, 0, 0);
    }
  };

  load_chunk(0);
  write_chunk(0, 0);
  __syncthreads();
  int cur = 0;
  for (int c = 0; c < nch; c++) {
    if (c + 1 < nch) load_chunk(c + 1);
    compute(cur);
    if (c + 1 < nch) write_chunk(c + 1, cur ^ 1);
    __syncthreads();
    cur ^= 1;
  }

  // non-atomic bf16 partial-G slab write
  ushort* Gs = Gslab + (size_t)b * 65536;
#pragma unroll
  for (int s = 0; s < 4; s++)
#pragma unroll
    for (int t = 0; t < 2; t++) {
      const int n0c = wcol + 32 * t + l31;
#pragma unroll
      for (int r = 0; r < 16; r++) {
        const int row = wrow + 32 * s + (r & 3) + 8 * (r >> 2) + 4 * lhi;
        Gs[row * 256 + n0c] = f2bf(acc[s][t][r]);
      }
    }

  // column-sum slab (non-atomic)
  __syncthreads();
  float* fl = (float*)sbT;  // scratch
#pragma unroll
  for (int i = 0; i < 8; i++) fl[rp * 256 + fg * 8 + i] = cs[i];
  __syncthreads();
  if (tid < 256) {
    float v = 0.0f;
    for (int j = 0; j < 16; j++) v += fl[j * 256 + tid];
    csl[(size_t)b * 256 + tid] = v;
  }
}

// reduce bf16 slabs -> fp32 G; also vsum and <G,Q>/<G,K2> partials (non-atomic)
__global__ void k_Gr(const ushort* __restrict__ Gslab, const float* __restrict__ csl,
                     const float* __restrict__ Q, const float* __restrict__ K2,
                     float* __restrict__ G, float* __restrict__ vsum,
                     float2* __restrict__ spart, int nslab) {
  __shared__ float red[4];
  const int b = blockIdx.x, t = threadIdx.x;
  const int i = b * 256 + t;
  float s0 = 0, s1 = 0, s2 = 0, s3 = 0;
  int j = 0;
  for (; j + 3 < nslab; j += 4) {
    s0 += bf2f(Gslab[(size_t)j * 65536 + i]);
    s1 += bf2f(Gslab[(size_t)(j + 1) * 65536 + i]);
    s2 += bf2f(Gslab[(size_t)(j + 2) * 65536 + i]);
    s3 += bf2f(Gslab[(size_t)(j + 3) * 65536 + i]);
  }
  float s = s0 + s1 + s2 + s3;
  for (; j < nslab; j++) s += bf2f(Gslab[(size_t)j * 65536 + i]);
  G[i] = s;
  float dq = block_sum(s * Q[i], red);
  float dk = block_sum(s * K2[i], red);
  if (t == 0) spart[b] = make_float2(dq, dk);
  float v = 0.0f;
  for (int u = t; u < nslab; u += 256) v += csl[(size_t)u * 256 + b];
  v = block_sum(v, red);
  if (t == 0) vsum[b] = v;
}

// per-iteration small products; block 258 finalizes scal
__global__ void k_small(const float* __restrict__ G, const float* __restrict__ vsum,
                        const float* __restrict__ P, const float* __restrict__ pb,
                        const float* __restrict__ wb, const float* __restrict__ sconst,
                        const float* __restrict__ qb, const float* __restrict__ kbv,
                        const float2* __restrict__ spart,
                        ushort* __restrict__ Mt, float* __restrict__ cvec,
                        float* __restrict__ dvec, float* __restrict__ scal, int N) {
  __shared__ float red[4];
  const int b = blockIdx.x, tid = threadIdx.x;
  if (b < 256) {
    float acc = 0.0f;
    for (int m = 0; m < H; m++) acc = fmaf(P[b * H + m], G[m * H + tid], acc);
    Mt[(size_t)tid * H + b] = f2bf(acc + pb[b] * vsum[tid]);
  } else if (b == 256) {
    float acc = 0.0f;
    for (int f = 0; f < H; f++) acc = fmaf(wb[f], G[f * H + tid], acc);
    cvec[tid] = acc + sconst[0] * vsum[tid];
  } else if (b == 257) {
    float acc = 0.0f;
    for (int m = 0; m < H; m++) acc = fmaf(P[tid * H + m], vsum[m], acc);
    dvec[tid] = acc + (float)N * pb[tid];
  } else {
    float2 sp = spart[tid];
    float dq = block_sum(sp.x, red);
    float dk = block_sum(sp.y, red);
    float s1 = block_sum(qb[tid] * vsum[tid], red);
    float s2 = block_sum(kbv[tid] * vsum[tid], red);
    float s3 = block_sum(wb[tid] * vsum[tid], red);
    if (tid == 0) {
      float sq = dq + 2.0f * s1 + (float)N * sconst[1];
      float sk = dk + 2.0f * s2 + (float)N * sconst[2];
      scal[2] = 1.0f / (sqrtf(sq) * sqrtf(sk));
      scal[3] = s3 + (float)N * sconst[0];
    }
  }
}

// fused k_C: phase 1 computes num = R*M via MFMA into bf16 LDS; phase 2 = den,
// fp8 gather, blend, LN, readout. 16KB LDS + min-4-waves/EU for occupancy.
__global__ __launch_bounds__(256, 4) void k_C(
    const ushort* __restrict__ Rb, ushort* __restrict__ Rnext,
    const ushort* __restrict__ Mt, const unsigned* __restrict__ Rf8,
    const int* __restrict__ eb, const float* __restrict__ invs,
    const float* __restrict__ cvec, const float* __restrict__ dvec,
    const float* __restrict__ vsum, const float* __restrict__ scal,
    const int* __restrict__ offs16, const int* __restrict__ deg,
    const float* __restrict__ alphap, const float* __restrict__ gamma,
    const float* __restrict__ beta, const float* __restrict__ Wr,
    const float* __restrict__ br, const float* __restrict__ wgt,
    float* __restrict__ out, int N, int layer, int last) {
  __shared__ __align__(16) ushort lnum[32 * 256];  // 16 KB (bf16)
  const int tid = threadIdx.x, lane = tid & 63, wv = tid >> 6;
  const int half = lane >> 5, hl = lane & 31;
  const int d0 = hl * 8;
  const int nb0 = blockIdx.x * 32;

  // ---- phase 1: num tile via MFMA (A rows from Rb, B cols from Mt[n][k]) ----
  {
    f32x16 a0, a1;
#pragma unroll
    for (int e = 0; e < 16; e++) { a0[e] = 0.0f; a1[e] = 0.0f; }
    const int wcol = wv * 64;
    const ushort* aptr = Rb + (size_t)(nb0 + hl) * H;  // rows beyond N: garbage ok (unread)
    const ushort* bptr0 = Mt + (size_t)(wcol + hl) * H;
    const ushort* bptr1 = Mt + (size_t)(wcol + 32 + hl) * H;
    for (int kc = 0; kc < 16; kc++) {
      const int kb = kc * 16 + half * 8;
      FragU fa, fb0, fb1;
      *(int4*)fa.u = *(const int4*)(aptr + kb);
      *(int4*)fb0.u = *(const int4*)(bptr0 + kb);
      *(int4*)fb1.u = *(const int4*)(bptr1 + kb);
      a0 = __builtin_amdgcn_mfma_f32_32x32x16_bf16(fa.v, fb0.v, a0, 0, 0, 0);
      a1 = __builtin_amdgcn_mfma_f32_32x32x16_bf16(fa.v, fb1.v, a1, 0, 0, 0);
    }
#pragma unroll
    for (int r = 0; r < 16; r++) {
      const int row = (r & 3) + 8 * (r >> 2) + 4 * half;
      lnum[row * 256 + wcol + hl] = f2bf(a0[r]);
      lnum[row * 256 + wcol + 32 + hl] = f2bf(a1[r]);
    }
  }
  __syncthreads();

  const float invn = scal[2], denc = scal[3];
  const float al = alphap[0], om = 1.0f - al;
  const float4 dvA = *(const float4*)&dvec[d0];
  const float4 dvB = *(const float4*)&dvec[d0 + 4];
  const float4 cvA = *(const float4*)&cvec[d0];
  const float4 cvB = *(const float4*)&cvec[d0 + 4];
  const float4 vsA = *(const float4*)&vsum[d0];
  const float4 vsB = *(const float4*)&vsum[d0 + 4];
  const float4 gmA = *(const float4*)&gamma[d0];
  const float4 gmB = *(const float4*)&gamma[d0 + 4];
  const float4 btA = *(const float4*)&beta[d0];
  const float4 btB = *(const float4*)&beta[d0 + 4];
  const float4 wrA = *(const float4*)&Wr[layer * H + d0];
  const float4 wrB = *(const float4*)&Wr[layer * H + d0 + 4];
  const float wl = wgt[layer], bl = br[layer];

  for (int r = 0; r < 4; r++) {
    const int lr = wv * 8 + r * 2 + half;
    const int n = nb0 + lr;
    const bool valid = n < N;
    const int ns = valid ? n : 0;

    const int4 rv = *(const int4*)&Rb[(size_t)ns * H + d0];
    const ushort* rp = (const ushort*)&rv;
    const int4 nv = *(const int4*)&lnum[lr * 256 + d0];
    const ushort* np = (const ushort*)&nv;
    float old[8], num[8];
#pragma unroll
    for (int j = 0; j < 8; j++) { old[j] = bf2f(rp[j]); num[j] = bf2f(np[j]); }

    float p = old[0] * dvA.x + old[1] * dvA.y + old[2] * dvA.z + old[3] * dvA.w +
              old[4] * dvB.x + old[5] * dvB.y + old[6] * dvB.z + old[7] * dvB.w;
    p = half_sum(p);
    const float rden = 1.0f / ((p + denc) * invn + (float)N);

    f32x2 a01 = {0.f, 0.f}, a23 = {0.f, 0.f}, a45 = {0.f, 0.f}, a67 = {0.f, 0.f};
    const int st = offs16[ns];
    const int nbch = valid ? ((deg[ns] + 15) >> 4) : 0;
    const int4* pe = (const int4*)(eb + st);
    const int woff = hl * 2;
    for (int b = 0; b < nbch; b++, pe += 4) {
      int4 q0 = pe[0], q1 = pe[1], q2 = pe[2], q3 = pe[3];
      const int srcs[16] = {q0.x, q0.y, q0.z, q0.w, q1.x, q1.y, q1.z, q1.w,
                            q2.x, q2.y, q2.z, q2.w, q3.x, q3.y, q3.z, q3.w};
      uint2 g[16];
#pragma unroll
      for (int i = 0; i < 16; i++)
        g[i] = *(const uint2*)&Rf8[((size_t)srcs[i] << 6) + woff];
#pragma unroll
      for (int i = 0; i < 16; i++) {
        unpack_fp8x2_acc(a01, a23, g[i].x);
        unpack_fp8x2_acc(a45, a67, g[i].y);
      }
    }
    const float sn = invs[ns];
    float ag[8] = {a01[0] * sn, a01[1] * sn, a23[0] * sn, a23[1] * sn,
                   a45[0] * sn, a45[1] * sn, a67[0] * sn, a67[1] * sn};

    const float cva[8] = {cvA.x, cvA.y, cvA.z, cvA.w, cvB.x, cvB.y, cvB.z, cvB.w};
    const float vsa[8] = {vsA.x, vsA.y, vsA.z, vsA.w, vsB.x, vsB.y, vsB.z, vsB.w};
    float hv[8];
#pragma unroll
    for (int j = 0; j < 8; j++)
      hv[j] = al * (((num[j] + cva[j]) * invn + vsa[j]) * rden + ag[j]) + om * old[j];

    float s = 0.0f, s2 = 0.0f;
#pragma unroll
    for (int j = 0; j < 8; j++) { s += hv[j]; s2 += hv[j] * hv[j]; }
    s = half_sum(s);
    s2 = half_sum(s2);
    const float mu = s * (1.0f / H);
    const float var = s2 * (1.0f / H) - mu * mu;
    const float rs = rsqrtf(var + LN_EPS);

    const float gma[8] = {gmA.x, gmA.y, gmA.z, gmA.w, gmB.x, gmB.y, gmB.z, gmB.w};
    const float bta[8] = {btA.x, btA.y, btA.z, btA.w, btB.x, btB.y, btB.z, btB.w};
    const float wra[8] = {wrA.x, wrA.y, wrA.z, wrA.w, wrB.x, wrB.y, wrB.z, wrB.w};
    float y[8], rp2 = 0.0f;
    ushort yo[8];
#pragma unroll
    for (int j = 0; j < 8; j++) {
      y[j] = (hv[j] - mu) * rs * gma[j] + bta[j];
      yo[j] = f2bf(y[j]);
      rp2 += y[j] * wra[j];
    }
    if (!last && valid) *(int4*)&Rnext[(size_t)n * H + d0] = *(int4*)yo;
    rp2 = half_sum(rp2);
    if (hl == 0 && valid) out[n] += wl * (rp2 + bl);
  }
}

// ---------------- host ----------------

extern "C" void kernel_launch(void* const* d_in, const int* in_sizes, int n_in,
                              void* d_out, int out_size, void* d_ws, size_t ws_size,
                              hipStream_t stream) {
  const float* x = (const float*)d_in[0];
  const int* ei = (const int*)d_in[1];
  const float* W1 = (const float*)d_in[2];
  const float* b1 = (const float*)d_in[3];
  const float* Wq = (const float*)d_in[4];
  const float* bq = (const float*)d_in[5];
  const float* Wk = (const float*)d_in[6];
  const float* bk = (const float*)d_in[7];
  const float* gamma = (const float*)d_in[8];
  const float* beta = (const float*)d_in[9];
  const float* alphap = (const float*)d_in[10];
  const float* Wr = (const float*)d_in[11];
  const float* br = (const float*)d_in[12];
  const float* wgt = (const float*)d_in[13];
  float* out = (float*)d_out;

  const int N = in_sizes[0] / FIN;
  const int E = in_sizes[1] / 2;
  const int* row = ei;
  const int* col = ei + E;

  char* w = (char*)d_ws;
  auto alloc = [&](size_t bytes) -> char* {
    char* p = w;
    w += (bytes + 255) & ~(size_t)255;
    return p;
  };
  const size_t RB = (size_t)(N + 128) * H * sizeof(ushort);
  ushort* Rb0 = (ushort*)alloc(RB);
  ushort* Rb1 = (ushort*)alloc(RB);   // aliased as super-bin record scratch in setup
  ushort* Gslab = (ushort*)alloc((size_t)256 * 65536 * sizeof(ushort));  // 32 MB
  unsigned* Rf8 = (unsigned*)alloc((size_t)(N + 1) * 64 * sizeof(unsigned));  // +1 zero row
  ushort* Mt = (ushort*)alloc(H * H * sizeof(ushort));
  float* G = (float*)alloc(H * H * sizeof(float));
  float* vsum = (float*)alloc(1024);
  float* scal = (float*)alloc(256);
  float* cvec = (float*)alloc(1024);
  float* dvec = (float*)alloc(1024);
  float* P = (float*)alloc(H * H * sizeof(float));
  float* Q = (float*)alloc(H * H * sizeof(float));
  float* K2 = (float*)alloc(H * H * sizeof(float));
  float* pb = (float*)alloc(1024);
  float* qb = (float*)alloc(1024);
  float* wb = (float*)alloc(1024);
  float* kb = (float*)alloc(1024);
  float* sconst = (float*)alloc(256);
  int* deg = (int*)alloc((size_t)N * 4);
  float* invs = (float*)alloc((size_t)N * 4);
  int* offs16 = (int*)alloc((size_t)(N + 1) * 4);
  int* bsum = (int*)alloc(1024 * 4);
  int* gcnt = (int*)alloc(64 * 4);
  const int nbG = 256;  // even chunk partition
  float* csl = (float*)alloc((size_t)nbG * 256 * sizeof(float));
  float2* spart = (float2*)alloc(256 * sizeof(float2));
  size_t EPAD = (size_t)E + 16 * (size_t)N;
  EPAD = (EPAD + 3) & ~(size_t)3;
  int* eb = (int*)alloc(EPAD * sizeof(int));

  const int NSB = (N + (1 << SBW) - 1) >> SBW;  // super-bins (<=64 for N<=131072)
  int cap2 = (E / (NSB > 0 ? NSB : 1)) * 2 + 4096;
  cap2 = (cap2 + 3) & ~3;
  unsigned* breg = (unsigned*)Rb1;  // NSB*cap2*4B <= RB

  hipMemsetAsync(gcnt, 0, 64 * 4, stream);
  hipMemsetAsync(Rf8 + (size_t)N * 64, 0, 64 * sizeof(unsigned), stream);

  const int nblk = (N + 1023) / 1024;
  const int nbB1 = (E + EPB - 1) / EPB;
  k_b1<<<nbB1, 512, 0, stream>>>(row, col, breg, gcnt, cap2, E, NSB);
  k_degB2<<<NSB, 512, 0, stream>>>(breg, gcnt, cap2, deg, invs, N);
  k_scan1<<<nblk, 1024, 0, stream>>>(deg, offs16, bsum, N);
  k_scan2<<<1, 1024, 0, stream>>>(bsum, nblk);
  k_b2<<<NSB, 512, 0, stream>>>(breg, gcnt, cap2, offs16, bsum, eb, N);
  k_prep<<<769, 256, 0, stream>>>(Wq, Wk, bq, bk, P, Q, K2, pb, qb, wb, kb, sconst);
  const int gRows16 = (N + 15) / 16;
  k_fc1<<<gRows16, 256, 0, stream>>>(x, W1, b1, Wr, br, wgt, Rb0, out, N);

  const int gRows32 = (N + 31) / 32;
  ushort* Rc = Rb0;
  ushort* Rn = Rb1;
  for (int it = 1; it <= 3; ++it) {
    k_Gm<<<nbG, 512, 0, stream>>>(Rc, invs, Gslab, Rf8, csl, N);
    k_Gr<<<256, 256, 0, stream>>>(Gslab, csl, Q, K2, G, vsum, spart, nbG);
    k_small<<<259, 256, 0, stream>>>(G, vsum, P, pb, wb, sconst, qb, kb, spart,
                                     Mt, cvec, dvec, scal, N);
    k_C<<<gRows32, 256, 0, stream>>>(Rc, Rn, Mt, Rf8, eb, invs, cvec, dvec, vsum, scal,
                                     offs16, deg, alphap, gamma, beta, Wr, br, wgt, out,
                                     N, it, (it == 3) ? 1 : 0);
    ushort* t = Rc; Rc = Rn; Rn = t;
  }
}